// Round 5
// baseline (735.711 us; speedup 1.0000x reference)
//
#include <hip/hip_runtime.h>
#include <stdint.h>

#define NV 4096
#define NE 8192
#define FV 128
#define FE 64
#define FOUT 128

typedef unsigned short u16;
typedef __attribute__((ext_vector_type(8))) short short8;
typedef __attribute__((ext_vector_type(4))) float f32x4;
typedef __attribute__((ext_vector_type(16))) float f32x16;
typedef __attribute__((ext_vector_type(4))) unsigned short u16x4;

__device__ __forceinline__ u16 f2bf(float f) {
  uint32_t u = __builtin_bit_cast(uint32_t, f);
  u += 0x7fffu + ((u >> 16) & 1u);   // round-to-nearest-even
  return (u16)(u >> 16);
}
__device__ __forceinline__ float bf2f(u16 h) {
  return __builtin_bit_cast(float, (uint32_t)h << 16);
}

#define AS1(p) ((__attribute__((address_space(1))) void*)(void*)(p))
#define AS3(p) ((__attribute__((address_space(3))) void*)(p))

// ------------------- d[e] = dot(H_e[e,:], p)  + fused H_e copy to out tuple slot 2
__global__ __launch_bounds__(256) void k_edge_dot(const float* __restrict__ He,
                                                  const float* __restrict__ p,
                                                  float* __restrict__ d,
                                                  float* __restrict__ out) {
  const int lane = threadIdx.x & 63;
  const int gw = blockIdx.x * 4 + (threadIdx.x >> 6);
  const float pv = p[lane];
  for (int e = gw; e < NE; e += 512) {
    float h = He[(size_t)e * FE + lane];
    out[(size_t)NV * FOUT + (size_t)e * FE + lane] = h;   // He copy (coalesced)
    float v = h * pv;
    #pragma unroll
    for (int off = 32; off > 0; off >>= 1) v += __shfl_down(v, off);
    if (lane == 0) d[e] = v;
  }
}

// --------------------------- Ta = bf16(T * d[col]), Tb = bf16(T)  (8 elems/thread, 16B stores)
__global__ __launch_bounds__(256) void k_convert(const float* __restrict__ T,
                                                 const float* __restrict__ d,
                                                 u16* __restrict__ Ta,
                                                 u16* __restrict__ Tb) {
  size_t idx = ((size_t)blockIdx.x * 256 + threadIdx.x) * 8;
  f32x4 t0 = *(const f32x4*)&T[idx];
  f32x4 t1 = *(const f32x4*)&T[idx + 4];
  int e = (int)(idx & (NE - 1));
  f32x4 d0 = *(const f32x4*)&d[e];
  f32x4 d1 = *(const f32x4*)&d[e + 4];
  short8 a, b;
  a[0] = (short)f2bf(t0.x * d0.x); a[1] = (short)f2bf(t0.y * d0.y);
  a[2] = (short)f2bf(t0.z * d0.z); a[3] = (short)f2bf(t0.w * d0.w);
  a[4] = (short)f2bf(t1.x * d1.x); a[5] = (short)f2bf(t1.y * d1.y);
  a[6] = (short)f2bf(t1.z * d1.z); a[7] = (short)f2bf(t1.w * d1.w);
  b[0] = (short)f2bf(t0.x); b[1] = (short)f2bf(t0.y);
  b[2] = (short)f2bf(t0.z); b[3] = (short)f2bf(t0.w);
  b[4] = (short)f2bf(t1.x); b[5] = (short)f2bf(t1.y);
  b[6] = (short)f2bf(t1.z); b[7] = (short)f2bf(t1.w);
  *(short8*)&Ta[idx] = a;
  *(short8*)&Tb[idx] = b;
}

// ---------- HWt[n][i] = bf16( sum_f Hv[i][f] * W[f][n] )  — W staged in LDS, 8 rows/block
__global__ __launch_bounds__(256) void k_hw(const float* __restrict__ Hv,
                                            const float* __restrict__ W,
                                            u16* __restrict__ HWt) {
  __shared__ float sW[FV * FOUT];   // 64 KB
  __shared__ float sH[8 * FV];      // 4 KB
  const int tid = threadIdx.x;
  const int i0 = blockIdx.x * 8;
  #pragma unroll
  for (int k = 0; k < 16; ++k)
    *(f32x4*)&sW[k * 1024 + tid * 4] = *(const f32x4*)&W[k * 1024 + tid * 4];
  *(f32x4*)&sH[tid * 4] = *(const f32x4*)&Hv[(size_t)i0 * FV + tid * 4];
  __syncthreads();
  const int n = tid & 127;
  const int rh = tid >> 7;          // 0..1 -> rows rh*4 .. rh*4+3
  float acc[4] = {0.f, 0.f, 0.f, 0.f};
  #pragma unroll 4
  for (int f = 0; f < FV; ++f) {
    float wv = sW[f * FOUT + n];
    #pragma unroll
    for (int rr = 0; rr < 4; ++rr)
      acc[rr] += sH[(rh * 4 + rr) * FV + f] * wv;
  }
  #pragma unroll
  for (int rr = 0; rr < 4; ++rr)
    HWt[(size_t)n * NV + i0 + rh * 4 + rr] = f2bf(acc[rr]);
}

// ---------------------------------------------------------------------------
// Full M = Ta @ Tb^T GEMM, 256x256 tile, BK=64, 8 waves (2Mx4N), 512 threads,
// r3's 8-phase counted-vmcnt schedule, now on v_mfma_f32_32x32x16_bf16
// (2495 TF pipe vs ~2100 for 16x16x32; half the MFMA instruction count).
// Grid = 256 blocks = 1/CU.
//
// Fragments: per wave 128x64 out = 4(mi) x 2(ni) frags of 32x32, 16 f32 acc
// each. Operand mapping: row=lane&31, k=(lane>>5)*8+j. Frag LDS read = b128
// at (row, 16B-slot s=k16*2+(lane>>5)); swizzle phys = s ^ (row&3) ->
// exactly 8 lanes per 16B bank-column (wave64 floor, conflict-free).
// Staging source permutation (tid&3)^((tid>>2)&3) is the same involution.
//
// LDS regions (u16 offs): A: b0k0=0 b0k1=8192 b1k0=16384 b1k1=24576; B:+32768.
// STG rotation: P1:(t+1).Ak1  P2:(t+2).Bk0  P3:(t+2).Ak0  P4:(t+2).Bk1
//   P5:(t+2).Ak1  P6:(t+3).Bk0  P7:(t+3).Ak0  P8:(t+3).Bk1.
// vmcnt(6) at P4 retires tile t+1; at P8 retires tile t+2. 3 STG (6 loads)
// always in flight; never drains to 0 in-loop.
// Epilogue: drain, LDS-transpose [256][260] bf16, coalesced eye-mask*adjv.
// ---------------------------------------------------------------------------
__global__ __launch_bounds__(512, 2) void k_gemm_m(const u16* __restrict__ Ta,
                                                   const u16* __restrict__ Tb,
                                                   const float* __restrict__ adjv,
                                                   u16* __restrict__ adjA) {
  __shared__ __align__(16) u16 smem[66560];   // 130 KB (main loop uses [0,65536))

  const int bi = blockIdx.x >> 4;
  const int bj = blockIdx.x & 15;
  const int tile_m = bi * 256;
  const int tile_n = bj * 256;
  const int tid = threadIdx.x;
  const int lane = tid & 63;
  const int wid = tid >> 6;
  const int wr = wid >> 2;          // 0..1  (M half)
  const int wc = wid & 3;           // 0..3  (N quarter)
  const int row32 = lane & 31;
  const int hi = lane >> 5;

  // swizzled 16B-slot offsets (u16 units) for k16 = 0,1 within a 32-k region
  const int swz0 = ((hi)     ^ (row32 & 3)) * 8;
  const int swz1 = ((2 + hi) ^ (row32 & 3)) * 8;

  // ---- staging addresses (per thread, constant over the loop)
  const int srow = tid >> 2;                              // 0..127 (r=0 rows)
  const int sslot = (tid & 3) ^ ((tid >> 2) & 3);         // pre-swizzled source slot
  const u16* gA0 = Ta + (size_t)(tile_m + srow) * NE + sslot * 8;
  const u16* gA1 = gA0 + (size_t)128 * NE;
  const u16* gB0 = Tb + (size_t)(tile_n + srow) * NE + sslot * 8;
  const u16* gB1 = gB0 + (size_t)128 * NE;
  const int ldsO0 = (wid * 64) * 8;
  const int ldsO1 = (512 + wid * 64) * 8;

#define STG(gp0, gp1, roff, kcol)                                                                 \
  do {                                                                                            \
    __builtin_amdgcn_global_load_lds(AS1((gp0) + (kcol)), AS3(&smem[(roff) + ldsO0]), 16, 0, 0);  \
    __builtin_amdgcn_global_load_lds(AS1((gp1) + (kcol)), AS3(&smem[(roff) + ldsO1]), 16, 0, 0);  \
  } while (0)

  f32x16 acc[4][2] = {};
  short8 aF[2][2], bF[2][2];        // [m2|ni][k16]

  const int arow32 = (wr * 128 + row32) * 32;   // + mi*1024 + swz
  const int brow32 = (wc * 64 + row32) * 32;    // + ni*1024 + swz (+32768 region)

#define LDSA(b, kk, mh)                                                                            \
  do { _Pragma("unroll")                                                                           \
    for (int m2 = 0; m2 < 2; ++m2) {                                                               \
      const int ab = (b)*16384 + (kk)*8192 + arow32 + ((mh)*2 + m2) * 1024;                        \
      aF[m2][0] = *(const short8*)&smem[ab + swz0];                                                \
      aF[m2][1] = *(const short8*)&smem[ab + swz1];                                                \
    }                                                                                              \
  } while (0)

#define LDSB(b, kk)                                                                                \
  do { _Pragma("unroll")                                                                           \
    for (int ni = 0; ni < 2; ++ni) {                                                               \
      const int bb = 32768 + (b)*16384 + (kk)*8192 + brow32 + ni * 1024;                           \
      bF[ni][0] = *(const short8*)&smem[bb + swz0];                                                \
      bF[ni][1] = *(const short8*)&smem[bb + swz1];                                                \
    }                                                                                              \
  } while (0)

#define MMH(mh)                                                                                    \
  do { _Pragma("unroll")                                                                           \
    for (int k16 = 0; k16 < 2; ++k16) { _Pragma("unroll")                                          \
      for (int m2 = 0; m2 < 2; ++m2) { _Pragma("unroll")                                           \
        for (int ni = 0; ni < 2; ++ni)                                                             \
          acc[(mh)*2+m2][ni] = __builtin_amdgcn_mfma_f32_32x32x16_bf16(                            \
              aF[m2][k16], bF[ni][k16], acc[(mh)*2+m2][ni], 0, 0, 0);                              \
      }                                                                                            \
    }                                                                                              \
  } while (0)

#define BARF()  do { __builtin_amdgcn_s_barrier(); asm volatile("" ::: "memory"); } while (0)
#define LGKM0() do { asm volatile("s_waitcnt lgkmcnt(0)" ::: "memory"); \
                     __builtin_amdgcn_sched_barrier(0); } while (0)
#define VM6()   asm volatile("s_waitcnt vmcnt(6)" ::: "memory")
#define PRIO1() __builtin_amdgcn_s_setprio(1)
#define PRIO0() __builtin_amdgcn_s_setprio(0)

  // ---- prologue: stage t0{Bk0,Ak0,Bk1,Ak1}, t1{Bk0,Ak0,Bk1}; gate to t0-resident
  STG(gB0, gB1, 32768, 0);
  STG(gA0, gA1, 0,     0);
  STG(gB0, gB1, 40960, 32);
  STG(gA0, gA1, 8192,  32);
  STG(gB0, gB1, 49152, 64);
  STG(gA0, gA1, 16384, 64);
  STG(gB0, gB1, 57344, 96);
  VM6();          // 14 in flight -> retire oldest 8 = tile0 fully resident
  BARF();

  for (int it = 0; it < 64; ++it) {
    const int t = it * 2;
    const int k1 = (t + 1) * 64;
    const int k2 = (t + 2 < 128 ? t + 2 : 127) * 64;   // clamped dummy at tail
    const int k3 = (t + 3 < 128 ? t + 3 : 127) * 64;

    // P1: (b0,k0,mh0); stage (t+1).Ak1 -> b1
    LDSB(0, 0); LDSA(0, 0, 0);
    STG(gA0, gA1, 24576, k1 + 32);
    BAR_P1: BARF(); LGKM0();
    PRIO1(); MMH(0); PRIO0();
    BARF();

    // P2: (b0,k0,mh1); stage (t+2).Bk0 -> b0 (freed P1)
    LDSA(0, 0, 1);
    STG(gB0, gB1, 32768, k2);
    BARF(); LGKM0();
    PRIO1(); MMH(1); PRIO0();
    BARF();

    // P3: (b0,k1,mh0); stage (t+2).Ak0 -> b0 (freed P2)
    LDSB(0, 1); LDSA(0, 1, 0);
    STG(gA0, gA1, 0, k2);
    BARF(); LGKM0();
    PRIO1(); MMH(0); PRIO0();
    BARF();

    // P4: (b0,k1,mh1); stage (t+2).Bk1 -> b0 (freed P3); counted vmcnt
    LDSA(0, 1, 1);
    STG(gB0, gB1, 40960, k2 + 32);
    BARF(); LGKM0();
    PRIO1(); MMH(1); PRIO0();
    VM6();                                          // tile t+1 resident
    BARF();

    // P5: (b1,k0,mh0); stage (t+2).Ak1 -> b0 (freed P4)
    LDSB(1, 0); LDSA(1, 0, 0);
    STG(gA0, gA1, 8192, k2 + 32);
    BARF(); LGKM0();
    PRIO1(); MMH(0); PRIO0();
    BARF();

    // P6: (b1,k0,mh1); stage (t+3).Bk0 -> b1 (freed P5)
    LDSA(1, 0, 1);
    STG(gB0, gB1, 49152, k3);
    BARF(); LGKM0();
    PRIO1(); MMH(1); PRIO0();
    BARF();

    // P7: (b1,k1,mh0); stage (t+3).Ak0 -> b1 (freed P6)
    LDSB(1, 1); LDSA(1, 1, 0);
    STG(gA0, gA1, 16384, k3);
    BARF(); LGKM0();
    PRIO1(); MMH(0); PRIO0();
    BARF();

    // P8: (b1,k1,mh1); stage (t+3).Bk1 -> b1 (freed P7); counted vmcnt
    LDSA(1, 1, 1);
    STG(gB0, gB1, 57344, k3 + 32);
    BARF(); LGKM0();
    PRIO1(); MMH(1); PRIO0();
    VM6();                                          // tile t+2 resident
    BARF();
  }

  // ---- epilogue: drain, LDS-transpose, coalesced mask+store
  asm volatile("s_waitcnt vmcnt(0) lgkmcnt(0)" ::: "memory");
  __syncthreads();
  // scatter acc (32x32 C/D: col=lane&31, row=(reg&3)+8*(reg>>2)+4*hi) -> bf16 LDS [256][260]
  #pragma unroll
  for (int mi = 0; mi < 4; ++mi) {
    #pragma unroll
    for (int ni = 0; ni < 2; ++ni) {
      const int colb = wc * 64 + ni * 32 + row32;
      const int rowb = wr * 128 + mi * 32 + 4 * hi;
      #pragma unroll
      for (int reg = 0; reg < 16; ++reg) {
        const int row = rowb + (reg & 3) + 8 * (reg >> 2);
        smem[row * 260 + colb] = f2bf(acc[mi][ni][reg]);
      }
    }
  }
  __syncthreads();
  const int ep_r = tid >> 4;           // 0..31
  const int ep_c = (tid & 15) * 4;     // 16 lanes -> 64 consecutive cols per j
  for (int pass = 0; pass < 8; ++pass) {
    const int row = pass * 32 + ep_r;
    const int gr = tile_m + row;
    const size_t gbase = (size_t)gr * NV + tile_n;
    #pragma unroll
    for (int j = 0; j < 4; ++j) {
      const int col = ep_c + j * 64;
      const int gc = tile_n + col;
      u16x4 m4 = *(const u16x4*)&smem[row * 260 + col];
      f32x4 av = *(const f32x4*)&adjv[gbase + col];
      u16x4 o;
      o.x = f2bf(((gr == gc + 0) ? 1.0f : bf2f(m4.x)) * av.x);
      o.y = f2bf(((gr == gc + 1) ? 1.0f : bf2f(m4.y)) * av.y);
      o.z = f2bf(((gr == gc + 2) ? 1.0f : bf2f(m4.z)) * av.z);
      o.w = f2bf(((gr == gc + 3) ? 1.0f : bf2f(m4.w)) * av.w);
      *(u16x4*)&adjA[gbase + col] = o;
    }
  }

#undef STG
#undef LDSA
#undef LDSB
#undef MMH
#undef BARF
#undef LGKM0
#undef VM6
#undef PRIO1
#undef PRIO0
}

// ---------------------------------------------------------------------------
// part[ks][i][n] = sum_{k in chunk ks} adjA[i][k] * HWt[n][k]   (no atomics)
// ---------------------------------------------------------------------------
#define KSPLIT 8
__global__ __launch_bounds__(256) void k_gemm_out(const u16* __restrict__ A,
                                                  const u16* __restrict__ B,
                                                  float* __restrict__ part) {
  __shared__ __align__(16) u16 lA[128 * 32];
  __shared__ __align__(16) u16 lB[128 * 32];
  const int K = NV;
  const int tile_m = blockIdx.y * 128;
  const int kbeg = blockIdx.x * (K / KSPLIT);
  const int kend = kbeg + (K / KSPLIT);
  const int tid = threadIdx.x;
  const int lane = tid & 63;
  const int wave = tid >> 6;
  const int wm = (wave >> 1) * 64;
  const int wn = (wave & 1) * 64;
  const int row16 = lane & 15;
  const int quad = lane >> 4;

  f32x4 acc[4][4] = {};

  for (int k0 = kbeg; k0 < kend; k0 += 32) {
    __syncthreads();
    #pragma unroll
    for (int r = 0; r < 2; ++r) {
      const int chunk = r * 256 + wave * 64 + lane;
      const int row = chunk >> 2;
      const int cc = chunk & 3;
      const u16* ga = A + ((size_t)(tile_m + row) * K + k0 + cc * 8);
      const u16* gb = B + ((size_t)row * K + k0 + cc * 8);   // N=128: full B tile
      __builtin_amdgcn_global_load_lds(AS1(ga), AS3(&lA[(r * 256 + wave * 64) * 8]), 16, 0, 0);
      __builtin_amdgcn_global_load_lds(AS1(gb), AS3(&lB[(r * 256 + wave * 64) * 8]), 16, 0, 0);
    }
    __syncthreads();
    short8 a[4], b[4];
    #pragma unroll
    for (int mi = 0; mi < 4; ++mi)
      a[mi] = *(const short8*)&lA[(wm + mi * 16 + row16) * 32 + quad * 8];
    #pragma unroll
    for (int ni = 0; ni < 4; ++ni)
      b[ni] = *(const short8*)&lB[(wn + ni * 16 + row16) * 32 + quad * 8];
    #pragma unroll
    for (int mi = 0; mi < 4; ++mi)
      #pragma unroll
      for (int ni = 0; ni < 4; ++ni)
        acc[mi][ni] = __builtin_amdgcn_mfma_f32_16x16x32_bf16(a[mi], b[ni], acc[mi][ni], 0, 0, 0);
  }

  float* pdst = part + (size_t)blockIdx.x * NV * FOUT;
  #pragma unroll
  for (int mi = 0; mi < 4; ++mi) {
    #pragma unroll
    for (int ni = 0; ni < 4; ++ni) {
      const int gc = wn + ni * 16 + row16;
      #pragma unroll
      for (int r = 0; r < 4; ++r) {
        const int gr = tile_m + wm + mi * 16 + quad * 4 + r;
        pdst[(size_t)gr * FOUT + gc] = acc[mi][ni][r];
      }
    }
  }
}

// ---------------------- out[i][n] = bias[n] + sum_ks part[ks][i][n]
__global__ __launch_bounds__(256) void k_reduce(const float* __restrict__ part,
                                                const float* __restrict__ bias,
                                                float* __restrict__ out) {
  size_t idx = ((size_t)blockIdx.x * 256 + threadIdx.x) * 4;
  f32x4 s = *(const f32x4*)&bias[idx & (FOUT - 1)];
  #pragma unroll
  for (int ks = 0; ks < KSPLIT; ++ks)
    s += *(const f32x4*)&part[(size_t)ks * NV * FOUT + idx];
  *(f32x4*)&out[idx] = s;
}

extern "C" void kernel_launch(void* const* d_in, const int* in_sizes, int n_in,
                              void* d_out, int out_size, void* d_ws, size_t ws_size,
                              hipStream_t stream) {
  const float* Hv   = (const float*)d_in[0];
  const float* He   = (const float*)d_in[1];
  // d_in[2] = adj_e : unused in node_layer=True path
  const float* adjv = (const float*)d_in[3];
  const float* T    = (const float*)d_in[4];
  const float* W    = (const float*)d_in[5];
  const float* p    = (const float*)d_in[6];
  const float* bias = (const float*)d_in[7];
  float* out = (float*)d_out;

  // ws layout (~178 MB):
  //   [0,32KB) d | [1MB,2MB) HWt | [2MB,66MB) Ta | [66MB,130MB) Tb
  //   [130MB,162MB) adjA | [162MB,178MB) part (8 x NV x FOUT f32)
  char* ws = (char*)d_ws;
  float* dvec = (float*)ws;
  u16* HWt    = (u16*)(ws + ((size_t)1 << 20));
  u16* Ta     = (u16*)(ws + ((size_t)2 << 20));
  u16* Tb     = (u16*)(ws + ((size_t)2 << 20) + ((size_t)64 << 20));
  u16* adjA   = (u16*)(ws + ((size_t)2 << 20) + ((size_t)128 << 20));
  float* part = (float*)(ws + ((size_t)2 << 20) + ((size_t)160 << 20));

  k_edge_dot<<<128, 256, 0, stream>>>(He, p, dvec, out);
  k_convert<<<(NV * NE) / (256 * 8), 256, 0, stream>>>(T, dvec, Ta, Tb);
  k_hw<<<NV / 8, 256, 0, stream>>>(Hv, W, HWt);
  k_gemm_m<<<256, 512, 0, stream>>>(Ta, Tb, adjv, adjA);
  k_gemm_out<<<dim3(KSPLIT, NV / 128), 256, 0, stream>>>(adjA, HWt, part);
  k_reduce<<<(NV * FOUT) / (256 * 4), 256, 0, stream>>>(part, bias, out);
}